// Round 4
// baseline (1146.439 us; speedup 1.0000x reference)
//
#include <hip/hip_runtime.h>
#include <hip/hip_bf16.h>
#include <math.h>

#define N_NODES 50000
#define D_FEAT  128
#define HIDDEN  256
#define CLASSES 40
#define N_EDGES 800000

typedef unsigned int  u32;
typedef unsigned short u16;
typedef __attribute__((ext_vector_type(8))) short short8;
typedef __attribute__((ext_vector_type(4))) float floatx4;

__device__ __forceinline__ float bf_lo(u32 w) { union { u32 i; float f; } u; u.i = w << 16; return u.f; }
__device__ __forceinline__ float bf_hi(u32 w) { union { u32 i; float f; } u; u.i = w & 0xffff0000u; return u.f; }
__device__ __forceinline__ u16 f2bf(float f) {
  union { float f; u32 i; } u; u.f = f; u32 i = u.i;
  return (u16)((i + 0x7fffu + ((i >> 16) & 1u)) >> 16);  // RNE
}
__device__ __forceinline__ u32 packbf(float a, float b) { return (u32)f2bf(a) | ((u32)f2bf(b) << 16); }

// ---- kernel 0: probe edge_index storage dtype (int64 vs int32) -------------
__global__ void detect_kernel(const long long* __restrict__ e64, int* __restrict__ flag) {
  __shared__ int ok;
  if (threadIdx.x == 0) ok = 1;
  __syncthreads();
  long long v = e64[(size_t)threadIdx.x * 3125];
  if (v < 0 || v >= N_NODES) ok = 0;
  __syncthreads();
  if (threadIdx.x == 0) *flag = ok;  // 1 => int64 storage
}

// ---- kernel 1: decode edges + degree histogram -----------------------------
__global__ __launch_bounds__(256) void convert_hist_kernel(
    const void* __restrict__ eraw, const int* __restrict__ flag,
    int* __restrict__ src, int* __restrict__ dst, int* __restrict__ counts) {
  int e = blockIdx.x * 256 + threadIdx.x;
  int s, d;
  if (*flag) {
    const long long* p = (const long long*)eraw;
    s = (int)p[e]; d = (int)p[N_EDGES + e];
  } else {
    const int* p = (const int*)eraw;
    s = p[e]; d = p[N_EDGES + e];
  }
  if ((u32)s >= N_NODES || (u32)d >= N_NODES) { s = -1; d = -1; }
  src[e] = s; dst[e] = d;
  if (d >= 0) atomicAdd(counts + d, 1);
}

// ---- kernel 2: exclusive scan -> offsets[N+1], cursor copy -----------------
__global__ __launch_bounds__(1024) void prefix_kernel(
    const int* __restrict__ counts, int* __restrict__ offsets, int* __restrict__ cursor) {
  __shared__ int lds[1024];
  const int t = threadIdx.x;
  const int CH = 49;
  int b = t * CH, e = min(b + CH, N_NODES);
  int s = 0;
  for (int i = b; i < e; i++) s += counts[i];
  lds[t] = s;
  __syncthreads();
  for (int d = 1; d < 1024; d <<= 1) {
    int v = (t >= d) ? lds[t - d] : 0;
    __syncthreads();
    lds[t] += v;
    __syncthreads();
  }
  int run = lds[t] - s;
  for (int i = b; i < e; i++) { offsets[i] = run; cursor[i] = run; run += counts[i]; }
  if (t == 1023) offsets[N_NODES] = lds[1023];
}

// ---- kernel 3: scatter edges into CSR-by-dst -------------------------------
__global__ __launch_bounds__(256) void scatter_kernel(
    const int* __restrict__ src, const int* __restrict__ dst,
    int* __restrict__ cursor, int* __restrict__ csr_src) {
  int e = blockIdx.x * 256 + threadIdx.x;
  int d = dst[e];
  if (d < 0) return;
  int pos = atomicAdd(cursor + d, 1);
  csr_src[pos] = src[e];
}

// ---- kernel 4: weights f32 -> bf16 packed buffer ---------------------------
// [0,32768) Wl1 | [32768,65536) Wr1 | [65536,75776) Wl2 | [75776,86016) Wr2
__global__ __launch_bounds__(256) void cvt_w_kernel(
    const float* __restrict__ Wl1, const float* __restrict__ Wr1,
    const float* __restrict__ Wl2, const float* __restrict__ Wr2,
    u16* __restrict__ wb) {
  int i = blockIdx.x * 256 + threadIdx.x;
  if (i < 32768)      wb[i] = f2bf(Wl1[i]);
  else if (i < 65536) wb[i] = f2bf(Wr1[i - 32768]);
  else if (i < 75776) wb[i] = f2bf(Wl2[i - 65536]);
  else if (i < 86016) wb[i] = f2bf(Wr2[i - 75776]);
}

// ---- kernel 5: layer-1 mean aggregation (gather), f32 ----------------------
__global__ __launch_bounds__(256) void gather1_kernel(
    const float* __restrict__ x, const int* __restrict__ offsets,
    const int* __restrict__ csr_src, float* __restrict__ agg1) {
  const int node = blockIdx.x * 4 + (threadIdx.x >> 6);
  const int lane = threadIdx.x & 63;
  int b = offsets[node], e = offsets[node + 1];
  float a0 = 0.f, a1 = 0.f;
  for (int i = b; i < e; i++) {
    int s = csr_src[i];
    float2 v = ((const float2*)(x + (size_t)s * D_FEAT))[lane];
    a0 += v.x; a1 += v.y;
  }
  float inv = 1.0f / (float)max(e - b, 1);
  float2 o; o.x = a0 * inv; o.y = a1 * inv;
  ((float2*)(agg1 + (size_t)node * D_FEAT))[lane] = o;
}

// ---- kernel 6: layer-1 GEMM, VALU reference (R3-proven, verbatim) ----------
__global__ __launch_bounds__(256) void gemm1_kernel(
    const float* __restrict__ agg1, const float* __restrict__ x,
    const float* __restrict__ Wl1, const float* __restrict__ Wr1,
    const float* __restrict__ bl1, u16* __restrict__ h) {
  __shared__ float A_lds[16 * D_FEAT];
  const int t  = threadIdx.x;
  const int tx = t & 63;
  const int ty = t >> 6;
  const int m0 = blockIdx.x * 16;

  float acc[4][4];
  #pragma unroll
  for (int i = 0; i < 4; i++)
    #pragma unroll
    for (int j = 0; j < 4; j++) acc[i][j] = 0.f;

  for (int ph = 0; ph < 2; ph++) {
    const float* A = (ph == 0 ? agg1 : x) + (size_t)m0 * D_FEAT;
    const float* W = (ph == 0 ? Wl1 : Wr1);
    __syncthreads();
    #pragma unroll
    for (int i = 0; i < 8; i++) {
      int idx = t + i * 256;
      A_lds[idx] = A[idx];
    }
    __syncthreads();
    for (int k = 0; k < D_FEAT; k += 4) {
      float4 w[4];
      #pragma unroll
      for (int j = 0; j < 4; j++)
        w[j] = *(const float4*)(W + (size_t)(tx * 4 + j) * D_FEAT + k);
      #pragma unroll
      for (int i = 0; i < 4; i++) {
        float4 a = *(const float4*)(&A_lds[(ty * 4 + i) * D_FEAT + k]);
        #pragma unroll
        for (int j = 0; j < 4; j++)
          acc[i][j] += a.x * w[j].x + a.y * w[j].y + a.z * w[j].z + a.w * w[j].w;
      }
    }
  }

  #pragma unroll
  for (int i = 0; i < 4; i++) {
    int row = m0 + ty * 4 + i;
    float v[4];
    #pragma unroll
    for (int j = 0; j < 4; j++) {
      float b = bl1[tx * 4 + j];
      float vv = acc[i][j] + b;
      v[j] = vv > 0.f ? vv : 0.f;
    }
    uint2 o; o.x = packbf(v[0], v[1]); o.y = packbf(v[2], v[3]);
    *(uint2*)(h + (size_t)row * HIDDEN + tx * 4) = o;
  }
}

// ---- kernel 7: layer-1 GEMM via MFMA (candidate under test) ----------------
// Fragment layouts per verified docs: A[m=lane&15][k=(lane>>4)*8+j];
// B (W row = n-side): n=lane&15, same k map; C/D: col=lane&15, row=(lane>>4)*4+reg.
__global__ __launch_bounds__(256) void gemm1_mfma_kernel(
    const float* __restrict__ agg1, const float* __restrict__ x,
    const u16* __restrict__ Wl1b, const u16* __restrict__ Wr1b,
    const float* __restrict__ bl1, u16* __restrict__ h) {
  const int lane = threadIdx.x & 63;
  const int wave = threadIdx.x >> 6;
  const int m0 = blockIdx.x * 16;
  const int ra = m0 + (lane & 15);
  const int ko = (lane >> 4) * 8;
  const int nb = wave * 64 + (lane & 15);

  floatx4 acc[4];
  #pragma unroll
  for (int t = 0; t < 4; t++) acc[t] = floatx4{0.f, 0.f, 0.f, 0.f};

  for (int ph = 0; ph < 2; ph++) {
    const float* A = (ph == 0 ? agg1 : x) + (size_t)ra * D_FEAT + ko;
    const u16* W = (ph == 0 ? Wl1b : Wr1b);
    #pragma unroll
    for (int kk = 0; kk < D_FEAT; kk += 32) {
      float4 a0 = *(const float4*)(A + kk);
      float4 a1 = *(const float4*)(A + kk + 4);
      union { short8 v; u32 w[4]; } af;
      af.w[0] = packbf(a0.x, a0.y);
      af.w[1] = packbf(a0.z, a0.w);
      af.w[2] = packbf(a1.x, a1.y);
      af.w[3] = packbf(a1.z, a1.w);
      #pragma unroll
      for (int t = 0; t < 4; t++) {
        short8 b = *(const short8*)(W + (size_t)(nb + t * 16) * D_FEAT + ko + kk);
        acc[t] = __builtin_amdgcn_mfma_f32_16x16x32_bf16(af.v, b, acc[t], 0, 0, 0);
      }
    }
  }

  #pragma unroll
  for (int t = 0; t < 4; t++) {
    int col = wave * 64 + t * 16 + (lane & 15);
    float bias = bl1[col];
    #pragma unroll
    for (int r = 0; r < 4; r++) {
      int row = m0 + (lane >> 4) * 4 + r;
      float v = acc[t][r] + bias;
      v = v > 0.f ? v : 0.f;
      h[(size_t)row * HIDDEN + col] = f2bf(v);
    }
  }
}

// ---- kernel 8: compare VALU h vs MFMA h, count large mismatches ------------
__global__ __launch_bounds__(256) void compare_kernel(
    const u16* __restrict__ a, const u16* __restrict__ b, int* __restrict__ mA) {
  int i = (blockIdx.x * 256 + threadIdx.x) * 8;  // 12.8M / 8 / 256 = 6250 blocks
  uint4 va = *(const uint4*)(a + i);
  uint4 vb = *(const uint4*)(b + i);
  int bad = 0;
  bad += fabsf(bf_lo(va.x) - bf_lo(vb.x)) > 0.25f;
  bad += fabsf(bf_hi(va.x) - bf_hi(vb.x)) > 0.25f;
  bad += fabsf(bf_lo(va.y) - bf_lo(vb.y)) > 0.25f;
  bad += fabsf(bf_hi(va.y) - bf_hi(vb.y)) > 0.25f;
  bad += fabsf(bf_lo(va.z) - bf_lo(vb.z)) > 0.25f;
  bad += fabsf(bf_hi(va.z) - bf_hi(vb.z)) > 0.25f;
  bad += fabsf(bf_lo(va.w) - bf_lo(vb.w)) > 0.25f;
  bad += fabsf(bf_hi(va.w) - bf_hi(vb.w)) > 0.25f;
  #pragma unroll
  for (int d = 1; d < 64; d <<= 1) bad += __shfl_xor(bad, d, 64);
  if ((threadIdx.x & 63) == 0 && bad) atomicAdd(mA, bad);
}

// ---- kernel 9: verdict signal — spins ~500us iff MFMA mismatched -----------
__global__ void check_kernel(const int* __restrict__ mA, int* __restrict__ sink) {
  int fa = (*mA > 1000) ? 1 : 0;
  int n = fa * 300000;  // ~1.2M dependent-FMA cycles ~ 500us
  float acc = (float)threadIdx.x;
  for (int i = 0; i < n; i++) acc = fmaf(acc, 1.0000001f, 1.0f);
  if (acc == 12345.678f) sink[0] = 1;  // never true; prevents DCE
}

// ---- kernel 10: layer-2 mean aggregation, selects verified h ---------------
__global__ __launch_bounds__(256) void gather2_kernel(
    const u16* __restrict__ h_mfma, const u16* __restrict__ h_valu,
    const int* __restrict__ mA, const int* __restrict__ offsets,
    const int* __restrict__ csr_src, u16* __restrict__ agg2) {
  const u16* h = (*mA <= 1000) ? h_mfma : h_valu;
  const int node = blockIdx.x * 4 + (threadIdx.x >> 6);
  const int lane = threadIdx.x & 63;
  int b = offsets[node], e = offsets[node + 1];
  float a0 = 0.f, a1 = 0.f, a2 = 0.f, a3 = 0.f;
  for (int i = b; i < e; i++) {
    int s = csr_src[i];
    uint2 w = ((const uint2*)(h + (size_t)s * HIDDEN))[lane];
    a0 += bf_lo(w.x); a1 += bf_hi(w.x);
    a2 += bf_lo(w.y); a3 += bf_hi(w.y);
  }
  float inv = 1.0f / (float)max(e - b, 1);
  uint2 o;
  o.x = packbf(a0 * inv, a1 * inv);
  o.y = packbf(a2 * inv, a3 * inv);
  ((uint2*)(agg2 + (size_t)node * HIDDEN))[lane] = o;
}

// ---- kernel 11: layer-2 GEMM + bias + log_softmax (R3-proven structure) ----
__global__ __launch_bounds__(256) void gemm2_kernel(
    const u16* __restrict__ agg2,
    const u16* __restrict__ h_mfma, const u16* __restrict__ h_valu,
    const int* __restrict__ mA,
    const float* __restrict__ Wl2, const float* __restrict__ Wr2,
    const float* __restrict__ bl2, float* __restrict__ out) {
  const u16* h = (*mA <= 1000) ? h_mfma : h_valu;
  __shared__ float A_lds[16 * 512];
  const int t  = threadIdx.x;
  const int tx = t & 63;
  const int ty = t >> 6;
  const int m0 = blockIdx.x * 16;

  #pragma unroll
  for (int i = 0; i < 8; i++) {
    int idx = t + i * 256;
    int r   = idx >> 7;
    int kk  = idx & 127;
    u32 wa = ((const u32*)(agg2 + (size_t)(m0 + r) * HIDDEN))[kk];
    u32 wh = ((const u32*)(h    + (size_t)(m0 + r) * HIDDEN))[kk];
    A_lds[r * 512 + kk * 2]           = bf_lo(wa);
    A_lds[r * 512 + kk * 2 + 1]       = bf_hi(wa);
    A_lds[r * 512 + 256 + kk * 2]     = bf_lo(wh);
    A_lds[r * 512 + 256 + kk * 2 + 1] = bf_hi(wh);
  }
  __syncthreads();

  float acc[4] = {0.f, 0.f, 0.f, 0.f};
  const bool active = (tx < CLASSES);
  if (active) {
    for (int k = 0; k < HIDDEN; k += 4) {
      float4 w = *(const float4*)(Wl2 + (size_t)tx * HIDDEN + k);
      #pragma unroll
      for (int i = 0; i < 4; i++) {
        float4 a = *(const float4*)(&A_lds[(ty * 4 + i) * 512 + k]);
        acc[i] += a.x * w.x + a.y * w.y + a.z * w.z + a.w * w.w;
      }
    }
    for (int k = 0; k < HIDDEN; k += 4) {
      float4 w = *(const float4*)(Wr2 + (size_t)tx * HIDDEN + k);
      #pragma unroll
      for (int i = 0; i < 4; i++) {
        float4 a = *(const float4*)(&A_lds[(ty * 4 + i) * 512 + 256 + k]);
        acc[i] += a.x * w.x + a.y * w.y + a.z * w.z + a.w * w.w;
      }
    }
  }
  float bias = active ? bl2[tx] : 0.f;

  #pragma unroll
  for (int i = 0; i < 4; i++) {
    float v = acc[i] + bias;
    float mx = active ? v : -INFINITY;
    #pragma unroll
    for (int d = 1; d < 64; d <<= 1) mx = fmaxf(mx, __shfl_xor(mx, d, 64));
    float ex = active ? expf(v - mx) : 0.f;
    float s = ex;
    #pragma unroll
    for (int d = 1; d < 64; d <<= 1) s += __shfl_xor(s, d, 64);
    float l = mx + logf(s);
    if (active) {
      int row = m0 + ty * 4 + i;
      out[(size_t)row * CLASSES + tx] = v - l;
    }
  }
}

extern "C" void kernel_launch(void* const* d_in, const int* in_sizes, int n_in,
                              void* d_out, int out_size, void* d_ws, size_t ws_size,
                              hipStream_t stream) {
  const float* x   = (const float*)d_in[0];
  const void*  ei  = d_in[1];
  const float* Wl1 = (const float*)d_in[2];
  const float* bl1 = (const float*)d_in[3];
  const float* Wr1 = (const float*)d_in[4];
  const float* Wl2 = (const float*)d_in[5];
  const float* bl2 = (const float*)d_in[6];
  const float* Wr2 = (const float*)d_in[7];

  char* ws = (char*)d_ws;
  size_t off = 0;
  int* flag    = (int*)(ws + off); off += 256;
  int* src     = (int*)(ws + off); off += (size_t)N_EDGES * 4;
  int* dst     = (int*)(ws + off); off += (size_t)N_EDGES * 4;
  int* csr     = (int*)(ws + off); off += (size_t)N_EDGES * 4;
  int* counts  = (int*)(ws + off); off += 200192;
  int* offsets = (int*)(ws + off); off += 200192;
  int* cursor  = (int*)(ws + off); off += 200192;
  int* mA      = (int*)(ws + off); off += 256;
  u16* wb      = (u16*)(ws + off); off += 172288;
  float* agg1  = (float*)(ws + off); off += (size_t)N_NODES * D_FEAT * 4;  // 25.6MB
  u16* hbuf0   = (u16*)(ws + off);   off += (size_t)N_NODES * HIDDEN * 2;  // 25.6MB
  u16* agg2    = (u16*)(ws + off);   off += (size_t)N_NODES * HIDDEN * 2;  // 25.6MB
  u16* hbuf1   = (u16*)(ws + off);   off += (size_t)N_NODES * HIDDEN * 2;  // 25.6MB (full tier only)

  const bool full = (ws_size >= off);  // need ~112.8MB for the MFMA A/B tier

  u16* Wl1b = wb;
  u16* Wr1b = wb + 32768;

  hipMemsetAsync(counts, 0, (size_t)N_NODES * 4, stream);
  detect_kernel<<<1, 256, 0, stream>>>((const long long*)ei, flag);
  convert_hist_kernel<<<N_EDGES / 256, 256, 0, stream>>>(ei, flag, src, dst, counts);
  prefix_kernel<<<1, 1024, 0, stream>>>(counts, offsets, cursor);
  scatter_kernel<<<N_EDGES / 256, 256, 0, stream>>>(src, dst, cursor, csr);
  gather1_kernel<<<N_NODES / 4, 256, 0, stream>>>(x, offsets, csr, agg1);
  gemm1_kernel<<<N_NODES / 16, 256, 0, stream>>>(agg1, x, Wl1, Wr1, bl1, hbuf0);

  const u16* h_m;
  const u16* h_v = hbuf0;
  const int* sel;
  if (full) {
    cvt_w_kernel<<<(86016 + 255) / 256, 256, 0, stream>>>(Wl1, Wr1, Wl2, Wr2, wb);
    gemm1_mfma_kernel<<<N_NODES / 16, 256, 0, stream>>>(agg1, x, Wl1b, Wr1b, bl1, hbuf1);
    hipMemsetAsync(mA, 0, 4, stream);
    compare_kernel<<<(N_NODES * HIDDEN) / (256 * 8), 256, 0, stream>>>(hbuf0, hbuf1, mA);
    check_kernel<<<1, 64, 0, stream>>>(mA, cursor);  // cursor dead post-scatter; used as DCE sink
    h_m = hbuf1; sel = mA;
  } else {
    h_m = hbuf0; sel = flag;  // *flag in {0,1} <= 1000 -> picks h_m == hbuf0; harmless
  }

  gather2_kernel<<<N_NODES / 4, 256, 0, stream>>>(h_m, h_v, sel, offsets, csr, agg2);
  gemm2_kernel<<<N_NODES / 16, 256, 0, stream>>>(agg2, h_m, h_v, sel, Wl2, Wr2, bl2, (float*)d_out);
}

// Round 5
// 659.315 us; speedup vs baseline: 1.7388x; 1.7388x over previous
//
#include <hip/hip_runtime.h>
#include <hip/hip_bf16.h>
#include <math.h>

#define N_NODES 50000
#define D_FEAT  128
#define HIDDEN  256
#define CLASSES 40
#define N_EDGES 800000

typedef unsigned int  u32;
typedef unsigned short u16;
typedef __attribute__((ext_vector_type(8))) short short8;
typedef __attribute__((ext_vector_type(4))) float floatx4;

__device__ __forceinline__ float bf_lo(u32 w) { union { u32 i; float f; } u; u.i = w << 16; return u.f; }
__device__ __forceinline__ float bf_hi(u32 w) { union { u32 i; float f; } u; u.i = w & 0xffff0000u; return u.f; }
__device__ __forceinline__ u16 f2bf(float f) {
  union { float f; u32 i; } u; u.f = f; u32 i = u.i;
  return (u16)((i + 0x7fffu + ((i >> 16) & 1u)) >> 16);  // RNE
}
__device__ __forceinline__ u32 packbf(float a, float b) { return (u32)f2bf(a) | ((u32)f2bf(b) << 16); }

// ---- kernel 0: probe edge_index storage dtype (int64 vs int32) -------------
__global__ void detect_kernel(const long long* __restrict__ e64, int* __restrict__ flag) {
  __shared__ int ok;
  if (threadIdx.x == 0) ok = 1;
  __syncthreads();
  long long v = e64[(size_t)threadIdx.x * 3125];
  if (v < 0 || v >= N_NODES) ok = 0;
  __syncthreads();
  if (threadIdx.x == 0) *flag = ok;  // 1 => int64 storage
}

// ---- kernel 1: decode edges + degree histogram -----------------------------
__global__ __launch_bounds__(256) void convert_hist_kernel(
    const void* __restrict__ eraw, const int* __restrict__ flag,
    int* __restrict__ src, int* __restrict__ dst, int* __restrict__ counts) {
  int e = blockIdx.x * 256 + threadIdx.x;
  int s, d;
  if (*flag) {
    const long long* p = (const long long*)eraw;
    s = (int)p[e]; d = (int)p[N_EDGES + e];
  } else {
    const int* p = (const int*)eraw;
    s = p[e]; d = p[N_EDGES + e];
  }
  if ((u32)s >= N_NODES || (u32)d >= N_NODES) { s = -1; d = -1; }
  src[e] = s; dst[e] = d;
  if (d >= 0) atomicAdd(counts + d, 1);
}

// ---- kernel 2: exclusive scan -> offsets[N+1], cursor copy -----------------
__global__ __launch_bounds__(1024) void prefix_kernel(
    const int* __restrict__ counts, int* __restrict__ offsets, int* __restrict__ cursor) {
  __shared__ int lds[1024];
  const int t = threadIdx.x;
  const int CH = 49;
  int b = t * CH, e = min(b + CH, N_NODES);
  int s = 0;
  for (int i = b; i < e; i++) s += counts[i];
  lds[t] = s;
  __syncthreads();
  for (int d = 1; d < 1024; d <<= 1) {
    int v = (t >= d) ? lds[t - d] : 0;
    __syncthreads();
    lds[t] += v;
    __syncthreads();
  }
  int run = lds[t] - s;
  for (int i = b; i < e; i++) { offsets[i] = run; cursor[i] = run; run += counts[i]; }
  if (t == 1023) offsets[N_NODES] = lds[1023];
}

// ---- kernel 3: scatter edges into CSR-by-dst -------------------------------
__global__ __launch_bounds__(256) void scatter_kernel(
    const int* __restrict__ src, const int* __restrict__ dst,
    int* __restrict__ cursor, int* __restrict__ csr_src) {
  int e = blockIdx.x * 256 + threadIdx.x;
  int d = dst[e];
  if (d < 0) return;
  int pos = atomicAdd(cursor + d, 1);
  csr_src[pos] = src[e];
}

// ---- kernel 4: x f32 -> bf16 ------------------------------------------------
__global__ __launch_bounds__(256) void cvt_x_kernel(
    const float* __restrict__ x, u16* __restrict__ xb) {
  int i = (blockIdx.x * 256 + threadIdx.x) * 4;  // 6.4M elems, 6250 blocks
  float4 v = *(const float4*)(x + i);
  u32* o = (u32*)(xb + i);
  o[0] = packbf(v.x, v.y);
  o[1] = packbf(v.z, v.w);
}

// ---- kernel 5: layer-1 weights f32 -> bf16 ----------------------------------
// [0,32768) Wl1 | [32768,65536) Wr1
__global__ __launch_bounds__(256) void cvt_w_kernel(
    const float* __restrict__ Wl1, const float* __restrict__ Wr1,
    u16* __restrict__ wb) {
  int i = blockIdx.x * 256 + threadIdx.x;  // 256 blocks * 256 = 65536
  if (i < 32768) wb[i] = f2bf(Wl1[i]);
  else           wb[i] = f2bf(Wr1[i - 32768]);
}

// ---- kernel 6: layer-1 mean aggregation (gather), bf16 ----------------------
__global__ __launch_bounds__(256) void gather1_kernel(
    const u16* __restrict__ xb, const int* __restrict__ offsets,
    const int* __restrict__ csr_src, u16* __restrict__ agg1) {
  const int node = blockIdx.x * 4 + (threadIdx.x >> 6);
  const int lane = threadIdx.x & 63;
  int b = offsets[node], e = offsets[node + 1];
  float a0 = 0.f, a1 = 0.f;
  for (int i = b; i < e; i++) {
    int s = csr_src[i];
    u32 w = ((const u32*)(xb + (size_t)s * D_FEAT))[lane];
    a0 += bf_lo(w); a1 += bf_hi(w);
  }
  float inv = 1.0f / (float)max(e - b, 1);
  ((u32*)(agg1 + (size_t)node * D_FEAT))[lane] = packbf(a0 * inv, a1 * inv);
}

// ---- kernel 7: layer-1 GEMM via MFMA (R4-verified layout, bf16 A loads) ----
// A[m=lane&15][k=(lane>>4)*8+j]; B n=lane&15 same k map; C/D col=lane&15,
// row=(lane>>4)*4+reg. Block = 4 waves; tile 16 rows x 256 cols.
__global__ __launch_bounds__(256) void gemm1_mfma_kernel(
    const u16* __restrict__ agg1, const u16* __restrict__ xb,
    const u16* __restrict__ Wl1b, const u16* __restrict__ Wr1b,
    const float* __restrict__ bl1, u16* __restrict__ h) {
  const int lane = threadIdx.x & 63;
  const int wave = threadIdx.x >> 6;
  const int m0 = blockIdx.x * 16;
  const int ra = m0 + (lane & 15);
  const int ko = (lane >> 4) * 8;
  const int nb = wave * 64 + (lane & 15);

  floatx4 acc[4];
  #pragma unroll
  for (int t = 0; t < 4; t++) acc[t] = floatx4{0.f, 0.f, 0.f, 0.f};

  #pragma unroll
  for (int ph = 0; ph < 2; ph++) {
    const u16* A = (ph == 0 ? agg1 : xb) + (size_t)ra * D_FEAT + ko;
    const u16* W = (ph == 0 ? Wl1b : Wr1b);
    #pragma unroll
    for (int kk = 0; kk < D_FEAT; kk += 32) {
      short8 a = *(const short8*)(A + kk);
      #pragma unroll
      for (int t = 0; t < 4; t++) {
        short8 b = *(const short8*)(W + (size_t)(nb + t * 16) * D_FEAT + ko + kk);
        acc[t] = __builtin_amdgcn_mfma_f32_16x16x32_bf16(a, b, acc[t], 0, 0, 0);
      }
    }
  }

  #pragma unroll
  for (int t = 0; t < 4; t++) {
    int col = wave * 64 + t * 16 + (lane & 15);
    float bias = bl1[col];
    #pragma unroll
    for (int r = 0; r < 4; r++) {
      int row = m0 + (lane >> 4) * 4 + r;
      float v = acc[t][r] + bias;
      v = v > 0.f ? v : 0.f;
      h[(size_t)row * HIDDEN + col] = f2bf(v);
    }
  }
}

// ---- kernel 8: layer-2 mean aggregation (gather), bf16 ----------------------
__global__ __launch_bounds__(256) void gather2_kernel(
    const u16* __restrict__ h, const int* __restrict__ offsets,
    const int* __restrict__ csr_src, u16* __restrict__ agg2) {
  const int node = blockIdx.x * 4 + (threadIdx.x >> 6);
  const int lane = threadIdx.x & 63;
  int b = offsets[node], e = offsets[node + 1];
  float a0 = 0.f, a1 = 0.f, a2 = 0.f, a3 = 0.f;
  for (int i = b; i < e; i++) {
    int s = csr_src[i];
    uint2 w = ((const uint2*)(h + (size_t)s * HIDDEN))[lane];
    a0 += bf_lo(w.x); a1 += bf_hi(w.x);
    a2 += bf_lo(w.y); a3 += bf_hi(w.y);
  }
  float inv = 1.0f / (float)max(e - b, 1);
  uint2 o;
  o.x = packbf(a0 * inv, a1 * inv);
  o.y = packbf(a2 * inv, a3 * inv);
  ((uint2*)(agg2 + (size_t)node * HIDDEN))[lane] = o;
}

// ---- kernel 9: layer-2 GEMM (VALU, R3-proven) + bias + log_softmax ----------
__global__ __launch_bounds__(256) void gemm2_kernel(
    const u16* __restrict__ agg2, const u16* __restrict__ h,
    const float* __restrict__ Wl2, const float* __restrict__ Wr2,
    const float* __restrict__ bl2, float* __restrict__ out) {
  __shared__ float A_lds[16 * 512];  // [row][0..255]=agg2, [256..511]=h
  const int t  = threadIdx.x;
  const int tx = t & 63;
  const int ty = t >> 6;
  const int m0 = blockIdx.x * 16;

  #pragma unroll
  for (int i = 0; i < 8; i++) {
    int idx = t + i * 256;
    int r   = idx >> 7;
    int kk  = idx & 127;
    u32 wa = ((const u32*)(agg2 + (size_t)(m0 + r) * HIDDEN))[kk];
    u32 wh = ((const u32*)(h    + (size_t)(m0 + r) * HIDDEN))[kk];
    A_lds[r * 512 + kk * 2]           = bf_lo(wa);
    A_lds[r * 512 + kk * 2 + 1]       = bf_hi(wa);
    A_lds[r * 512 + 256 + kk * 2]     = bf_lo(wh);
    A_lds[r * 512 + 256 + kk * 2 + 1] = bf_hi(wh);
  }
  __syncthreads();

  float acc[4] = {0.f, 0.f, 0.f, 0.f};
  const bool active = (tx < CLASSES);
  if (active) {
    for (int k = 0; k < HIDDEN; k += 4) {
      float4 w = *(const float4*)(Wl2 + (size_t)tx * HIDDEN + k);
      #pragma unroll
      for (int i = 0; i < 4; i++) {
        float4 a = *(const float4*)(&A_lds[(ty * 4 + i) * 512 + k]);
        acc[i] += a.x * w.x + a.y * w.y + a.z * w.z + a.w * w.w;
      }
    }
    for (int k = 0; k < HIDDEN; k += 4) {
      float4 w = *(const float4*)(Wr2 + (size_t)tx * HIDDEN + k);
      #pragma unroll
      for (int i = 0; i < 4; i++) {
        float4 a = *(const float4*)(&A_lds[(ty * 4 + i) * 512 + 256 + k]);
        acc[i] += a.x * w.x + a.y * w.y + a.z * w.z + a.w * w.w;
      }
    }
  }
  float bias = active ? bl2[tx] : 0.f;

  #pragma unroll
  for (int i = 0; i < 4; i++) {
    float v = acc[i] + bias;
    float mx = active ? v : -INFINITY;
    #pragma unroll
    for (int d = 1; d < 64; d <<= 1) mx = fmaxf(mx, __shfl_xor(mx, d, 64));
    float ex = active ? expf(v - mx) : 0.f;
    float s = ex;
    #pragma unroll
    for (int d = 1; d < 64; d <<= 1) s += __shfl_xor(s, d, 64);
    float l = mx + logf(s);
    if (active) {
      int row = m0 + ty * 4 + i;
      out[(size_t)row * CLASSES + tx] = v - l;
    }
  }
}

extern "C" void kernel_launch(void* const* d_in, const int* in_sizes, int n_in,
                              void* d_out, int out_size, void* d_ws, size_t ws_size,
                              hipStream_t stream) {
  const float* x   = (const float*)d_in[0];
  const void*  ei  = d_in[1];
  const float* Wl1 = (const float*)d_in[2];
  const float* bl1 = (const float*)d_in[3];
  const float* Wr1 = (const float*)d_in[4];
  const float* Wl2 = (const float*)d_in[5];
  const float* bl2 = (const float*)d_in[6];
  const float* Wr2 = (const float*)d_in[7];

  char* ws = (char*)d_ws;
  size_t off = 0;
  int* flag    = (int*)(ws + off); off += 256;
  int* src     = (int*)(ws + off); off += (size_t)N_EDGES * 4;           // 3.2MB
  int* dst     = (int*)(ws + off); off += (size_t)N_EDGES * 4;           // 3.2MB
  int* csr     = (int*)(ws + off); off += (size_t)N_EDGES * 4;           // 3.2MB
  int* counts  = (int*)(ws + off); off += 200192;
  int* offsets = (int*)(ws + off); off += 200192;
  int* cursor  = (int*)(ws + off); off += 200192;
  u16* wb      = (u16*)(ws + off); off += 131072;                        // 65536 bf16
  u16* xb      = (u16*)(ws + off); off += (size_t)N_NODES * D_FEAT * 2;  // 12.8MB
  u16* agg1    = (u16*)(ws + off); off += (size_t)N_NODES * D_FEAT * 2;  // 12.8MB
  u16* hbuf    = (u16*)(ws + off); off += (size_t)N_NODES * HIDDEN * 2;  // 25.6MB
  u16* agg2    = (u16*)(ws + off); off += (size_t)N_NODES * HIDDEN * 2;  // 25.6MB

  u16* Wl1b = wb;
  u16* Wr1b = wb + 32768;

  hipMemsetAsync(counts, 0, (size_t)N_NODES * 4, stream);
  detect_kernel<<<1, 256, 0, stream>>>((const long long*)ei, flag);
  convert_hist_kernel<<<N_EDGES / 256, 256, 0, stream>>>(ei, flag, src, dst, counts);
  prefix_kernel<<<1, 1024, 0, stream>>>(counts, offsets, cursor);
  scatter_kernel<<<N_EDGES / 256, 256, 0, stream>>>(src, dst, cursor, csr);
  cvt_x_kernel<<<(N_NODES * D_FEAT) / (256 * 4), 256, 0, stream>>>(x, xb);
  cvt_w_kernel<<<256, 256, 0, stream>>>(Wl1, Wr1, wb);
  gather1_kernel<<<N_NODES / 4, 256, 0, stream>>>(xb, offsets, csr, agg1);
  gemm1_mfma_kernel<<<N_NODES / 16, 256, 0, stream>>>(agg1, xb, Wl1b, Wr1b, bl1, hbuf);
  gather2_kernel<<<N_NODES / 4, 256, 0, stream>>>(hbuf, offsets, csr, agg2);
  gemm2_kernel<<<N_NODES / 16, 256, 0, stream>>>(agg2, hbuf, Wl2, Wr2, bl2, (float*)d_out);
}

// Round 6
// 522.202 us; speedup vs baseline: 2.1954x; 1.2626x over previous
//
#include <hip/hip_runtime.h>
#include <hip/hip_bf16.h>
#include <math.h>

#define N_NODES 50000
#define D_FEAT  128
#define HIDDEN  256
#define CLASSES 40
#define N_EDGES 800000
#define P2S 64   // p2 row stride (bf16) -> 128B aligned rows
#define R2S 48   // r2 row stride (f32)

typedef unsigned int  u32;
typedef unsigned short u16;
typedef __attribute__((ext_vector_type(8))) short short8;
typedef __attribute__((ext_vector_type(4))) float floatx4;

__device__ __forceinline__ float bf_lo(u32 w) { union { u32 i; float f; } u; u.i = w << 16; return u.f; }
__device__ __forceinline__ float bf_hi(u32 w) { union { u32 i; float f; } u; u.i = w & 0xffff0000u; return u.f; }
__device__ __forceinline__ float bf1(u16 h)   { union { u32 i; float f; } u; u.i = ((u32)h) << 16; return u.f; }
__device__ __forceinline__ u16 f2bf(float f) {
  union { float f; u32 i; } u; u.f = f; u32 i = u.i;
  return (u16)((i + 0x7fffu + ((i >> 16) & 1u)) >> 16);  // RNE
}
__device__ __forceinline__ u32 packbf(float a, float b) { return (u32)f2bf(a) | ((u32)f2bf(b) << 16); }

// ---- kernel 0: probe edge_index storage dtype (int64 vs int32) -------------
__global__ void detect_kernel(const long long* __restrict__ e64, int* __restrict__ flag) {
  __shared__ int ok;
  if (threadIdx.x == 0) ok = 1;
  __syncthreads();
  long long v = e64[(size_t)threadIdx.x * 3125];
  if (v < 0 || v >= N_NODES) ok = 0;
  __syncthreads();
  if (threadIdx.x == 0) *flag = ok;  // 1 => int64 storage
}

// ---- kernel 1: decode edges + degree histogram -----------------------------
__global__ __launch_bounds__(256) void convert_hist_kernel(
    const void* __restrict__ eraw, const int* __restrict__ flag,
    int* __restrict__ src, int* __restrict__ dst, int* __restrict__ counts) {
  int e = blockIdx.x * 256 + threadIdx.x;
  int s, d;
  if (*flag) {
    const long long* p = (const long long*)eraw;
    s = (int)p[e]; d = (int)p[N_EDGES + e];
  } else {
    const int* p = (const int*)eraw;
    s = p[e]; d = p[N_EDGES + e];
  }
  if ((u32)s >= N_NODES || (u32)d >= N_NODES) { s = -1; d = -1; }
  src[e] = s; dst[e] = d;
  if (d >= 0) atomicAdd(counts + d, 1);
}

// ---- kernel 2: exclusive scan -> offsets[N+1], cursor copy -----------------
__global__ __launch_bounds__(1024) void prefix_kernel(
    const int* __restrict__ counts, int* __restrict__ offsets, int* __restrict__ cursor) {
  __shared__ int lds[1024];
  const int t = threadIdx.x;
  const int CH = 49;
  int b = t * CH, e = min(b + CH, N_NODES);
  int s = 0;
  for (int i = b; i < e; i++) s += counts[i];
  lds[t] = s;
  __syncthreads();
  for (int d = 1; d < 1024; d <<= 1) {
    int v = (t >= d) ? lds[t - d] : 0;
    __syncthreads();
    lds[t] += v;
    __syncthreads();
  }
  int run = lds[t] - s;
  for (int i = b; i < e; i++) { offsets[i] = run; cursor[i] = run; run += counts[i]; }
  if (t == 1023) offsets[N_NODES] = lds[1023];
}

// ---- kernel 3: scatter edges into CSR-by-dst -------------------------------
__global__ __launch_bounds__(256) void scatter_kernel(
    const int* __restrict__ src, const int* __restrict__ dst,
    int* __restrict__ cursor, int* __restrict__ csr_src) {
  int e = blockIdx.x * 256 + threadIdx.x;
  int d = dst[e];
  if (d < 0) return;
  int pos = atomicAdd(cursor + d, 1);
  csr_src[pos] = src[e];
}

// ---- kernel 4: x f32 -> bf16 ------------------------------------------------
__global__ __launch_bounds__(256) void cvt_x_kernel(
    const float* __restrict__ x, u16* __restrict__ xb) {
  int i = (blockIdx.x * 256 + threadIdx.x) * 4;
  float4 v = *(const float4*)(x + i);
  u32* o = (u32*)(xb + i);
  o[0] = packbf(v.x, v.y);
  o[1] = packbf(v.z, v.w);
}

// ---- kernel 5: all weights f32 -> bf16 packed ------------------------------
// [0,32768) Wl1 | [32768,65536) Wr1 | [65536,75776) Wl2 | [75776,86016) Wr2
__global__ __launch_bounds__(256) void cvt_w_kernel(
    const float* __restrict__ Wl1, const float* __restrict__ Wr1,
    const float* __restrict__ Wl2, const float* __restrict__ Wr2,
    u16* __restrict__ wb) {
  int i = blockIdx.x * 256 + threadIdx.x;
  if (i < 32768)      wb[i] = f2bf(Wl1[i]);
  else if (i < 65536) wb[i] = f2bf(Wr1[i - 32768]);
  else if (i < 75776) wb[i] = f2bf(Wl2[i - 65536]);
  else if (i < 86016) wb[i] = f2bf(Wr2[i - 75776]);
}

// ---- kernel 6: layer-1 mean aggregation (gather), bf16 ----------------------
__global__ __launch_bounds__(256) void gather1_kernel(
    const u16* __restrict__ xb, const int* __restrict__ offsets,
    const int* __restrict__ csr_src, u16* __restrict__ agg1) {
  const int node = blockIdx.x * 4 + (threadIdx.x >> 6);
  const int lane = threadIdx.x & 63;
  int b = offsets[node], e = offsets[node + 1];
  float a0 = 0.f, a1 = 0.f;
  for (int i = b; i < e; i++) {
    int s = csr_src[i];
    u32 w = ((const u32*)(xb + (size_t)s * D_FEAT))[lane];
    a0 += bf_lo(w); a1 += bf_hi(w);
  }
  float inv = 1.0f / (float)max(e - b, 1);
  ((u32*)(agg1 + (size_t)node * D_FEAT))[lane] = packbf(a0 * inv, a1 * inv);
}

// ---- kernel 7: layer-1 GEMM via MFMA (R4/R5-verified) ----------------------
__global__ __launch_bounds__(256) void gemm1_mfma_kernel(
    const u16* __restrict__ agg1, const u16* __restrict__ xb,
    const u16* __restrict__ Wl1b, const u16* __restrict__ Wr1b,
    const float* __restrict__ bl1, u16* __restrict__ h) {
  const int lane = threadIdx.x & 63;
  const int wave = threadIdx.x >> 6;
  const int m0 = blockIdx.x * 16;
  const int ra = m0 + (lane & 15);
  const int ko = (lane >> 4) * 8;
  const int nb = wave * 64 + (lane & 15);

  floatx4 acc[4];
  #pragma unroll
  for (int t = 0; t < 4; t++) acc[t] = floatx4{0.f, 0.f, 0.f, 0.f};

  #pragma unroll
  for (int ph = 0; ph < 2; ph++) {
    const u16* A = (ph == 0 ? agg1 : xb) + (size_t)ra * D_FEAT + ko;
    const u16* W = (ph == 0 ? Wl1b : Wr1b);
    #pragma unroll
    for (int kk = 0; kk < D_FEAT; kk += 32) {
      short8 a = *(const short8*)(A + kk);
      #pragma unroll
      for (int t = 0; t < 4; t++) {
        short8 b = *(const short8*)(W + (size_t)(nb + t * 16) * D_FEAT + ko + kk);
        acc[t] = __builtin_amdgcn_mfma_f32_16x16x32_bf16(a, b, acc[t], 0, 0, 0);
      }
    }
  }

  #pragma unroll
  for (int t = 0; t < 4; t++) {
    int col = wave * 64 + t * 16 + (lane & 15);
    float bias = bl1[col];
    #pragma unroll
    for (int r = 0; r < 4; r++) {
      int row = m0 + (lane >> 4) * 4 + r;
      float v = acc[t][r] + bias;
      v = v > 0.f ? v : 0.f;
      h[(size_t)row * HIDDEN + col] = f2bf(v);
    }
  }
}

// ---- kernel 8: layer-2 dual projection via MFMA ----------------------------
// p2 = h @ Wl2^T (bf16, stride P2S) ; r2 = h @ Wr2^T + bl2 (f32, stride R2S).
// Wave per 16-row tile; 3 n-tiles cover 48 cols (40 valid, pad cols never read).
// Same verified fragment maps as gemm1_mfma.
__global__ __launch_bounds__(256) void gemm2ab_kernel(
    const u16* __restrict__ h, const u16* __restrict__ Wl2b,
    const u16* __restrict__ Wr2b, const float* __restrict__ bl2,
    u16* __restrict__ p2b, float* __restrict__ r2f) {
  const int lane = threadIdx.x & 63;
  const int wave = threadIdx.x >> 6;
  const int tile = blockIdx.x * 4 + wave;
  if (tile >= N_NODES / 16) return;
  const int m0 = tile * 16;
  const int ra = m0 + (lane & 15);
  const int ko = (lane >> 4) * 8;
  const int n15 = lane & 15;
  const int nrow0 = n15;
  const int nrow1 = 16 + n15;
  const int nrow2 = min(32 + n15, CLASSES - 1);  // clamp; lands in pad cols

  floatx4 accp[3], accr[3];
  #pragma unroll
  for (int t = 0; t < 3; t++) {
    accp[t] = floatx4{0.f, 0.f, 0.f, 0.f};
    accr[t] = floatx4{0.f, 0.f, 0.f, 0.f};
  }

  const u16* A  = h + (size_t)ra * HIDDEN + ko;
  const u16* L0 = Wl2b + (size_t)nrow0 * HIDDEN + ko;
  const u16* L1 = Wl2b + (size_t)nrow1 * HIDDEN + ko;
  const u16* L2 = Wl2b + (size_t)nrow2 * HIDDEN + ko;
  const u16* R0 = Wr2b + (size_t)nrow0 * HIDDEN + ko;
  const u16* R1 = Wr2b + (size_t)nrow1 * HIDDEN + ko;
  const u16* R2 = Wr2b + (size_t)nrow2 * HIDDEN + ko;

  #pragma unroll
  for (int kk = 0; kk < HIDDEN; kk += 32) {
    short8 a = *(const short8*)(A + kk);
    accp[0] = __builtin_amdgcn_mfma_f32_16x16x32_bf16(a, *(const short8*)(L0 + kk), accp[0], 0, 0, 0);
    accp[1] = __builtin_amdgcn_mfma_f32_16x16x32_bf16(a, *(const short8*)(L1 + kk), accp[1], 0, 0, 0);
    accp[2] = __builtin_amdgcn_mfma_f32_16x16x32_bf16(a, *(const short8*)(L2 + kk), accp[2], 0, 0, 0);
    accr[0] = __builtin_amdgcn_mfma_f32_16x16x32_bf16(a, *(const short8*)(R0 + kk), accr[0], 0, 0, 0);
    accr[1] = __builtin_amdgcn_mfma_f32_16x16x32_bf16(a, *(const short8*)(R1 + kk), accr[1], 0, 0, 0);
    accr[2] = __builtin_amdgcn_mfma_f32_16x16x32_bf16(a, *(const short8*)(R2 + kk), accr[2], 0, 0, 0);
  }

  #pragma unroll
  for (int t = 0; t < 3; t++) {
    int col = t * 16 + n15;
    float bias = bl2[min(col, CLASSES - 1)];
    #pragma unroll
    for (int r = 0; r < 4; r++) {
      int row = m0 + (lane >> 4) * 4 + r;
      p2b[(size_t)row * P2S + col] = f2bf(accp[t][r]);
      r2f[(size_t)row * R2S + col] = accr[t][r] + bias;
    }
  }
}

// ---- kernel 9: fused mean-gather of p2 + r2 add + log_softmax --------------
// Wave per node; lane = class. Each edge reads one aligned 128B p2 row.
__global__ __launch_bounds__(256) void final_kernel(
    const u16* __restrict__ p2b, const float* __restrict__ r2f,
    const int* __restrict__ offsets, const int* __restrict__ csr_src,
    float* __restrict__ out) {
  const int node = blockIdx.x * 4 + (threadIdx.x >> 6);
  const int lane = threadIdx.x & 63;
  int b = offsets[node], e = offsets[node + 1];
  float s = 0.f;
  for (int i = b; i < e; i++) {
    int sc = csr_src[i];
    s += bf1(p2b[(size_t)sc * P2S + lane]);  // lanes>=48 read pad (finite), discarded
  }
  float inv = 1.0f / (float)max(e - b, 1);
  const bool act = (lane < CLASSES);
  float v = act ? (s * inv + r2f[(size_t)node * R2S + lane]) : -INFINITY;
  float mx = v;
  #pragma unroll
  for (int d = 1; d < 64; d <<= 1) mx = fmaxf(mx, __shfl_xor(mx, d, 64));
  float ex = act ? expf(v - mx) : 0.f;
  float sum = ex;
  #pragma unroll
  for (int d = 1; d < 64; d <<= 1) sum += __shfl_xor(sum, d, 64);
  float l = mx + logf(sum);
  if (act) out[(size_t)node * CLASSES + lane] = v - l;
}

extern "C" void kernel_launch(void* const* d_in, const int* in_sizes, int n_in,
                              void* d_out, int out_size, void* d_ws, size_t ws_size,
                              hipStream_t stream) {
  const float* x   = (const float*)d_in[0];
  const void*  ei  = d_in[1];
  const float* Wl1 = (const float*)d_in[2];
  const float* bl1 = (const float*)d_in[3];
  const float* Wr1 = (const float*)d_in[4];
  const float* Wl2 = (const float*)d_in[5];
  const float* bl2 = (const float*)d_in[6];
  const float* Wr2 = (const float*)d_in[7];

  char* ws = (char*)d_ws;
  size_t off = 0;
  int* flag    = (int*)(ws + off); off += 256;
  int* src     = (int*)(ws + off); off += (size_t)N_EDGES * 4;             // 3.2MB
  int* dst     = (int*)(ws + off); off += (size_t)N_EDGES * 4;             // 3.2MB
  int* csr     = (int*)(ws + off); off += (size_t)N_EDGES * 4;             // 3.2MB
  int* counts  = (int*)(ws + off); off += 200192;
  int* offsets = (int*)(ws + off); off += 200192;
  int* cursor  = (int*)(ws + off); off += 200192;
  u16* wb      = (u16*)(ws + off); off += 172288;                          // 86016 bf16 padded
  u16* xb      = (u16*)(ws + off); off += (size_t)N_NODES * D_FEAT * 2;    // 12.8MB
  u16* agg1    = (u16*)(ws + off); off += (size_t)N_NODES * D_FEAT * 2;    // 12.8MB
  u16* hbuf    = (u16*)(ws + off); off += (size_t)N_NODES * HIDDEN * 2;    // 25.6MB
  u16* p2b     = (u16*)(ws + off); off += (size_t)N_NODES * P2S * 2;       // 6.4MB
  float* r2f   = (float*)(ws + off); off += (size_t)N_NODES * R2S * 4;     // 9.6MB

  u16* Wl1b = wb;
  u16* Wr1b = wb + 32768;
  u16* Wl2b = wb + 65536;
  u16* Wr2b = wb + 75776;

  hipMemsetAsync(counts, 0, (size_t)N_NODES * 4, stream);
  detect_kernel<<<1, 256, 0, stream>>>((const long long*)ei, flag);
  convert_hist_kernel<<<N_EDGES / 256, 256, 0, stream>>>(ei, flag, src, dst, counts);
  prefix_kernel<<<1, 1024, 0, stream>>>(counts, offsets, cursor);
  scatter_kernel<<<N_EDGES / 256, 256, 0, stream>>>(src, dst, cursor, csr);
  cvt_x_kernel<<<(N_NODES * D_FEAT) / (256 * 4), 256, 0, stream>>>(x, xb);
  cvt_w_kernel<<<(86016 + 255) / 256, 256, 0, stream>>>(Wl1, Wr1, Wl2, Wr2, wb);
  gather1_kernel<<<N_NODES / 4, 256, 0, stream>>>(xb, offsets, csr, agg1);
  gemm1_mfma_kernel<<<N_NODES / 16, 256, 0, stream>>>(agg1, xb, Wl1b, Wr1b, bl1, hbuf);
  gemm2ab_kernel<<<(N_NODES / 16 + 3) / 4, 256, 0, stream>>>(hbuf, Wl2b, Wr2b, bl2, p2b, r2f);
  final_kernel<<<N_NODES / 4, 256, 0, stream>>>(p2b, r2f, offsets, csr, (float*)d_out);
}

// Round 7
// 418.778 us; speedup vs baseline: 2.7376x; 1.2470x over previous
//
#include <hip/hip_runtime.h>
#include <hip/hip_bf16.h>
#include <math.h>

#define N_NODES 50000
#define D_FEAT  128
#define HIDDEN  256
#define CLASSES 40
#define N_EDGES 800000
#define P2S 64   // p2 row stride (bf16) -> 128B aligned rows
#define R2S 48   // r2 row stride (f32)
#define SCAN_NB 196  // 196*256 = 50176 >= N_NODES

typedef unsigned int  u32;
typedef unsigned short u16;
typedef __attribute__((ext_vector_type(8))) short short8;
typedef __attribute__((ext_vector_type(4))) float floatx4;

__device__ __forceinline__ float bf_lo(u32 w) { union { u32 i; float f; } u; u.i = w << 16; return u.f; }
__device__ __forceinline__ float bf_hi(u32 w) { union { u32 i; float f; } u; u.i = w & 0xffff0000u; return u.f; }
__device__ __forceinline__ float bf1(u16 h)   { union { u32 i; float f; } u; u.i = ((u32)h) << 16; return u.f; }
__device__ __forceinline__ u16 f2bf(float f) {
  union { float f; u32 i; } u; u.f = f; u32 i = u.i;
  return (u16)((i + 0x7fffu + ((i >> 16) & 1u)) >> 16);  // RNE
}
__device__ __forceinline__ u32 packbf(float a, float b) { return (u32)f2bf(a) | ((u32)f2bf(b) << 16); }

// ---- kernel 0: probe edge_index storage dtype (int64 vs int32) -------------
__global__ void detect_kernel(const long long* __restrict__ e64, int* __restrict__ flag) {
  __shared__ int ok;
  if (threadIdx.x == 0) ok = 1;
  __syncthreads();
  long long v = e64[(size_t)threadIdx.x * 3125];
  if (v < 0 || v >= N_NODES) ok = 0;
  __syncthreads();
  if (threadIdx.x == 0) *flag = ok;  // 1 => int64 storage
}

// ---- kernel 1: decode edges + degree histogram -----------------------------
__global__ __launch_bounds__(256) void convert_hist_kernel(
    const void* __restrict__ eraw, const int* __restrict__ flag,
    int* __restrict__ src, int* __restrict__ dst, int* __restrict__ counts) {
  int e = blockIdx.x * 256 + threadIdx.x;
  int s, d;
  if (*flag) {
    const long long* p = (const long long*)eraw;
    s = (int)p[e]; d = (int)p[N_EDGES + e];
  } else {
    const int* p = (const int*)eraw;
    s = p[e]; d = p[N_EDGES + e];
  }
  if ((u32)s >= N_NODES || (u32)d >= N_NODES) { s = -1; d = -1; }
  src[e] = s; dst[e] = d;
  if (d >= 0) atomicAdd(counts + d, 1);
}

// ---- kernels 2a/2b/2c: device-wide exclusive scan of counts ----------------
// scan1: per-block exclusive scan (coalesced) + block totals
__global__ __launch_bounds__(256) void scan1_kernel(
    const int* __restrict__ counts, int* __restrict__ offsets,
    int* __restrict__ blocksums) {
  __shared__ int lds[256];
  const int t = threadIdx.x;
  const int i = blockIdx.x * 256 + t;
  int c = (i < N_NODES) ? counts[i] : 0;
  lds[t] = c;
  __syncthreads();
  #pragma unroll
  for (int d = 1; d < 256; d <<= 1) {
    int v = (t >= d) ? lds[t - d] : 0;
    __syncthreads();
    lds[t] += v;
    __syncthreads();
  }
  if (i < N_NODES) offsets[i] = lds[t] - c;  // exclusive within block
  if (t == 255) blocksums[blockIdx.x] = lds[255];
}

// scan2: single block scans the 196 block totals -> exclusive btops + total
__global__ __launch_bounds__(256) void scan2_kernel(
    const int* __restrict__ blocksums, int* __restrict__ btops,
    int* __restrict__ offsets) {
  __shared__ int lds[256];
  const int t = threadIdx.x;
  int c = (t < SCAN_NB) ? blocksums[t] : 0;
  lds[t] = c;
  __syncthreads();
  #pragma unroll
  for (int d = 1; d < 256; d <<= 1) {
    int v = (t >= d) ? lds[t - d] : 0;
    __syncthreads();
    lds[t] += v;
    __syncthreads();
  }
  if (t < SCAN_NB) btops[t] = lds[t] - c;
  if (t == SCAN_NB - 1) offsets[N_NODES] = lds[t];  // grand total
}

// scan3: add block prefix, emit final offsets + cursor
__global__ __launch_bounds__(256) void scan3_kernel(
    int* __restrict__ offsets, const int* __restrict__ btops,
    int* __restrict__ cursor) {
  const int i = blockIdx.x * 256 + threadIdx.x;
  if (i >= N_NODES) return;
  int o = offsets[i] + btops[blockIdx.x];
  offsets[i] = o;
  cursor[i] = o;
}

// ---- kernel 3: scatter edges into CSR-by-dst -------------------------------
__global__ __launch_bounds__(256) void scatter_kernel(
    const int* __restrict__ src, const int* __restrict__ dst,
    int* __restrict__ cursor, int* __restrict__ csr_src) {
  int e = blockIdx.x * 256 + threadIdx.x;
  int d = dst[e];
  if (d < 0) return;
  int pos = atomicAdd(cursor + d, 1);
  csr_src[pos] = src[e];
}

// ---- kernel 4: x f32 -> bf16 ------------------------------------------------
__global__ __launch_bounds__(256) void cvt_x_kernel(
    const float* __restrict__ x, u16* __restrict__ xb) {
  int i = (blockIdx.x * 256 + threadIdx.x) * 4;
  float4 v = *(const float4*)(x + i);
  u32* o = (u32*)(xb + i);
  o[0] = packbf(v.x, v.y);
  o[1] = packbf(v.z, v.w);
}

// ---- kernel 5: all weights f32 -> bf16 packed ------------------------------
// [0,32768) Wl1 | [32768,65536) Wr1 | [65536,75776) Wl2 | [75776,86016) Wr2
__global__ __launch_bounds__(256) void cvt_w_kernel(
    const float* __restrict__ Wl1, const float* __restrict__ Wr1,
    const float* __restrict__ Wl2, const float* __restrict__ Wr2,
    u16* __restrict__ wb) {
  int i = blockIdx.x * 256 + threadIdx.x;
  if (i < 32768)      wb[i] = f2bf(Wl1[i]);
  else if (i < 65536) wb[i] = f2bf(Wr1[i - 32768]);
  else if (i < 75776) wb[i] = f2bf(Wl2[i - 65536]);
  else if (i < 86016) wb[i] = f2bf(Wr2[i - 75776]);
}

// ---- kernel 6: layer-1 mean aggregation (gather), bf16 ----------------------
__global__ __launch_bounds__(256) void gather1_kernel(
    const u16* __restrict__ xb, const int* __restrict__ offsets,
    const int* __restrict__ csr_src, u16* __restrict__ agg1) {
  const int node = blockIdx.x * 4 + (threadIdx.x >> 6);
  const int lane = threadIdx.x & 63;
  int b = offsets[node], e = offsets[node + 1];
  float a0 = 0.f, a1 = 0.f;
  for (int i = b; i < e; i++) {
    int s = csr_src[i];
    u32 w = ((const u32*)(xb + (size_t)s * D_FEAT))[lane];
    a0 += bf_lo(w); a1 += bf_hi(w);
  }
  float inv = 1.0f / (float)max(e - b, 1);
  ((u32*)(agg1 + (size_t)node * D_FEAT))[lane] = packbf(a0 * inv, a1 * inv);
}

// ---- kernel 7: layer-1 GEMM via MFMA (R4/R5-verified) ----------------------
__global__ __launch_bounds__(256) void gemm1_mfma_kernel(
    const u16* __restrict__ agg1, const u16* __restrict__ xb,
    const u16* __restrict__ Wl1b, const u16* __restrict__ Wr1b,
    const float* __restrict__ bl1, u16* __restrict__ h) {
  const int lane = threadIdx.x & 63;
  const int wave = threadIdx.x >> 6;
  const int m0 = blockIdx.x * 16;
  const int ra = m0 + (lane & 15);
  const int ko = (lane >> 4) * 8;
  const int nb = wave * 64 + (lane & 15);

  floatx4 acc[4];
  #pragma unroll
  for (int t = 0; t < 4; t++) acc[t] = floatx4{0.f, 0.f, 0.f, 0.f};

  #pragma unroll
  for (int ph = 0; ph < 2; ph++) {
    const u16* A = (ph == 0 ? agg1 : xb) + (size_t)ra * D_FEAT + ko;
    const u16* W = (ph == 0 ? Wl1b : Wr1b);
    #pragma unroll
    for (int kk = 0; kk < D_FEAT; kk += 32) {
      short8 a = *(const short8*)(A + kk);
      #pragma unroll
      for (int t = 0; t < 4; t++) {
        short8 b = *(const short8*)(W + (size_t)(nb + t * 16) * D_FEAT + ko + kk);
        acc[t] = __builtin_amdgcn_mfma_f32_16x16x32_bf16(a, b, acc[t], 0, 0, 0);
      }
    }
  }

  #pragma unroll
  for (int t = 0; t < 4; t++) {
    int col = wave * 64 + t * 16 + (lane & 15);
    float bias = bl1[col];
    #pragma unroll
    for (int r = 0; r < 4; r++) {
      int row = m0 + (lane >> 4) * 4 + r;
      float v = acc[t][r] + bias;
      v = v > 0.f ? v : 0.f;
      h[(size_t)row * HIDDEN + col] = f2bf(v);
    }
  }
}

// ---- kernel 8: layer-2 dual projection via MFMA (R6-verified) --------------
// p2 = h @ Wl2^T (bf16, stride P2S) ; r2 = h @ Wr2^T + bl2 (f32, stride R2S).
__global__ __launch_bounds__(256) void gemm2ab_kernel(
    const u16* __restrict__ h, const u16* __restrict__ Wl2b,
    const u16* __restrict__ Wr2b, const float* __restrict__ bl2,
    u16* __restrict__ p2b, float* __restrict__ r2f) {
  const int lane = threadIdx.x & 63;
  const int wave = threadIdx.x >> 6;
  const int tile = blockIdx.x * 4 + wave;
  if (tile >= N_NODES / 16) return;
  const int m0 = tile * 16;
  const int ra = m0 + (lane & 15);
  const int ko = (lane >> 4) * 8;
  const int n15 = lane & 15;
  const int nrow0 = n15;
  const int nrow1 = 16 + n15;
  const int nrow2 = min(32 + n15, CLASSES - 1);  // clamp; lands in pad cols

  floatx4 accp[3], accr[3];
  #pragma unroll
  for (int t = 0; t < 3; t++) {
    accp[t] = floatx4{0.f, 0.f, 0.f, 0.f};
    accr[t] = floatx4{0.f, 0.f, 0.f, 0.f};
  }

  const u16* A  = h + (size_t)ra * HIDDEN + ko;
  const u16* L0 = Wl2b + (size_t)nrow0 * HIDDEN + ko;
  const u16* L1 = Wl2b + (size_t)nrow1 * HIDDEN + ko;
  const u16* L2 = Wl2b + (size_t)nrow2 * HIDDEN + ko;
  const u16* R0 = Wr2b + (size_t)nrow0 * HIDDEN + ko;
  const u16* R1 = Wr2b + (size_t)nrow1 * HIDDEN + ko;
  const u16* R2 = Wr2b + (size_t)nrow2 * HIDDEN + ko;

  #pragma unroll
  for (int kk = 0; kk < HIDDEN; kk += 32) {
    short8 a = *(const short8*)(A + kk);
    accp[0] = __builtin_amdgcn_mfma_f32_16x16x32_bf16(a, *(const short8*)(L0 + kk), accp[0], 0, 0, 0);
    accp[1] = __builtin_amdgcn_mfma_f32_16x16x32_bf16(a, *(const short8*)(L1 + kk), accp[1], 0, 0, 0);
    accp[2] = __builtin_amdgcn_mfma_f32_16x16x32_bf16(a, *(const short8*)(L2 + kk), accp[2], 0, 0, 0);
    accr[0] = __builtin_amdgcn_mfma_f32_16x16x32_bf16(a, *(const short8*)(R0 + kk), accr[0], 0, 0, 0);
    accr[1] = __builtin_amdgcn_mfma_f32_16x16x32_bf16(a, *(const short8*)(R1 + kk), accr[1], 0, 0, 0);
    accr[2] = __builtin_amdgcn_mfma_f32_16x16x32_bf16(a, *(const short8*)(R2 + kk), accr[2], 0, 0, 0);
  }

  #pragma unroll
  for (int t = 0; t < 3; t++) {
    int col = t * 16 + n15;
    float bias = bl2[min(col, CLASSES - 1)];
    #pragma unroll
    for (int r = 0; r < 4; r++) {
      int row = m0 + (lane >> 4) * 4 + r;
      p2b[(size_t)row * P2S + col] = f2bf(accp[t][r]);
      r2f[(size_t)row * R2S + col] = accr[t][r] + bias;
    }
  }
}

// ---- kernel 9: fused mean-gather of p2 + r2 add + log_softmax (R6-verified)-
__global__ __launch_bounds__(256) void final_kernel(
    const u16* __restrict__ p2b, const float* __restrict__ r2f,
    const int* __restrict__ offsets, const int* __restrict__ csr_src,
    float* __restrict__ out) {
  const int node = blockIdx.x * 4 + (threadIdx.x >> 6);
  const int lane = threadIdx.x & 63;
  int b = offsets[node], e = offsets[node + 1];
  float s = 0.f;
  for (int i = b; i < e; i++) {
    int sc = csr_src[i];
    s += bf1(p2b[(size_t)sc * P2S + lane]);
  }
  float inv = 1.0f / (float)max(e - b, 1);
  const bool act = (lane < CLASSES);
  float v = act ? (s * inv + r2f[(size_t)node * R2S + lane]) : -INFINITY;
  float mx = v;
  #pragma unroll
  for (int d = 1; d < 64; d <<= 1) mx = fmaxf(mx, __shfl_xor(mx, d, 64));
  float ex = act ? expf(v - mx) : 0.f;
  float sum = ex;
  #pragma unroll
  for (int d = 1; d < 64; d <<= 1) sum += __shfl_xor(sum, d, 64);
  float l = mx + logf(sum);
  if (act) out[(size_t)node * CLASSES + lane] = v - l;
}

extern "C" void kernel_launch(void* const* d_in, const int* in_sizes, int n_in,
                              void* d_out, int out_size, void* d_ws, size_t ws_size,
                              hipStream_t stream) {
  const float* x   = (const float*)d_in[0];
  const void*  ei  = d_in[1];
  const float* Wl1 = (const float*)d_in[2];
  const float* bl1 = (const float*)d_in[3];
  const float* Wr1 = (const float*)d_in[4];
  const float* Wl2 = (const float*)d_in[5];
  const float* bl2 = (const float*)d_in[6];
  const float* Wr2 = (const float*)d_in[7];

  char* ws = (char*)d_ws;
  size_t off = 0;
  int* flag      = (int*)(ws + off); off += 256;
  int* src       = (int*)(ws + off); off += (size_t)N_EDGES * 4;             // 3.2MB
  int* dst       = (int*)(ws + off); off += (size_t)N_EDGES * 4;             // 3.2MB
  int* csr       = (int*)(ws + off); off += (size_t)N_EDGES * 4;             // 3.2MB
  int* counts    = (int*)(ws + off); off += 200192;
  int* offsets   = (int*)(ws + off); off += 200192;
  int* cursor    = (int*)(ws + off); off += 200192;
  int* blocksums = (int*)(ws + off); off += 1024;
  int* btops     = (int*)(ws + off); off += 1024;
  u16* wb        = (u16*)(ws + off); off += 172288;                          // 86016 bf16 padded
  u16* xb        = (u16*)(ws + off); off += (size_t)N_NODES * D_FEAT * 2;    // 12.8MB
  u16* agg1      = (u16*)(ws + off); off += (size_t)N_NODES * D_FEAT * 2;    // 12.8MB
  u16* hbuf      = (u16*)(ws + off); off += (size_t)N_NODES * HIDDEN * 2;    // 25.6MB
  u16* p2b       = (u16*)(ws + off); off += (size_t)N_NODES * P2S * 2;       // 6.4MB
  float* r2f     = (float*)(ws + off); off += (size_t)N_NODES * R2S * 4;     // 9.6MB

  u16* Wl1b = wb;
  u16* Wr1b = wb + 32768;
  u16* Wl2b = wb + 65536;
  u16* Wr2b = wb + 75776;

  hipMemsetAsync(counts, 0, (size_t)N_NODES * 4, stream);
  detect_kernel<<<1, 256, 0, stream>>>((const long long*)ei, flag);
  convert_hist_kernel<<<N_EDGES / 256, 256, 0, stream>>>(ei, flag, src, dst, counts);
  scan1_kernel<<<SCAN_NB, 256, 0, stream>>>(counts, offsets, blocksums);
  scan2_kernel<<<1, 256, 0, stream>>>(blocksums, btops, offsets);
  scan3_kernel<<<SCAN_NB, 256, 0, stream>>>(offsets, btops, cursor);
  scatter_kernel<<<N_EDGES / 256, 256, 0, stream>>>(src, dst, cursor, csr);
  cvt_x_kernel<<<(N_NODES * D_FEAT) / (256 * 4), 256, 0, stream>>>(x, xb);
  cvt_w_kernel<<<(86016 + 255) / 256, 256, 0, stream>>>(Wl1, Wr1, Wl2, Wr2, wb);
  gather1_kernel<<<N_NODES / 4, 256, 0, stream>>>(xb, offsets, csr, agg1);
  gemm1_mfma_kernel<<<N_NODES / 16, 256, 0, stream>>>(agg1, xb, Wl1b, Wr1b, bl1, hbuf);
  gemm2ab_kernel<<<(N_NODES / 16 + 3) / 4, 256, 0, stream>>>(hbuf, Wl2b, Wr2b, bl2, p2b, r2f);
  final_kernel<<<N_NODES / 4, 256, 0, stream>>>(p2b, r2f, offsets, csr, (float*)d_out);
}

// Round 8
// 339.342 us; speedup vs baseline: 3.3784x; 1.2341x over previous
//
#include <hip/hip_runtime.h>
#include <hip/hip_bf16.h>
#include <math.h>

#define N_NODES 50000
#define D_FEAT  128
#define HIDDEN  256
#define CLASSES 40
#define N_EDGES 800000
#define P2S 64   // p2 row stride (bf16) -> 128B aligned rows
#define R2S 48   // r2 row stride (f32)
#define SCAN_NB 196  // 196*256 = 50176 >= N_NODES

typedef unsigned int  u32;
typedef unsigned short u16;
typedef __attribute__((ext_vector_type(8))) short short8;
typedef __attribute__((ext_vector_type(4))) float floatx4;

__device__ __forceinline__ float bf_lo(u32 w) { union { u32 i; float f; } u; u.i = w << 16; return u.f; }
__device__ __forceinline__ float bf_hi(u32 w) { union { u32 i; float f; } u; u.i = w & 0xffff0000u; return u.f; }
__device__ __forceinline__ float bf1(u16 h)   { union { u32 i; float f; } u; u.i = ((u32)h) << 16; return u.f; }
__device__ __forceinline__ u16 f2bf(float f) {
  union { float f; u32 i; } u; u.f = f; u32 i = u.i;
  return (u16)((i + 0x7fffu + ((i >> 16) & 1u)) >> 16);  // RNE
}
__device__ __forceinline__ u32 packbf(float a, float b) { return (u32)f2bf(a) | ((u32)f2bf(b) << 16); }

// ---- kernel 0: probe edge_index storage dtype (int64 vs int32) -------------
__global__ void detect_kernel(const long long* __restrict__ e64, int* __restrict__ flag) {
  __shared__ int ok;
  if (threadIdx.x == 0) ok = 1;
  __syncthreads();
  long long v = e64[(size_t)threadIdx.x * 3125];
  if (v < 0 || v >= N_NODES) ok = 0;
  __syncthreads();
  if (threadIdx.x == 0) *flag = ok;  // 1 => int64 storage
}

// ---- kernel 1: decode edges + degree histogram -----------------------------
__global__ __launch_bounds__(256) void convert_hist_kernel(
    const void* __restrict__ eraw, const int* __restrict__ flag,
    int* __restrict__ src, int* __restrict__ dst, int* __restrict__ counts) {
  int e = blockIdx.x * 256 + threadIdx.x;
  int s, d;
  if (*flag) {
    const long long* p = (const long long*)eraw;
    s = (int)p[e]; d = (int)p[N_EDGES + e];
  } else {
    const int* p = (const int*)eraw;
    s = p[e]; d = p[N_EDGES + e];
  }
  if ((u32)s >= N_NODES || (u32)d >= N_NODES) { s = -1; d = -1; }
  src[e] = s; dst[e] = d;
  if (d >= 0) atomicAdd(counts + d, 1);
}

// ---- kernels 2a/2b/2c: device-wide exclusive scan of counts ----------------
__global__ __launch_bounds__(256) void scan1_kernel(
    const int* __restrict__ counts, int* __restrict__ offsets,
    int* __restrict__ blocksums) {
  __shared__ int lds[256];
  const int t = threadIdx.x;
  const int i = blockIdx.x * 256 + t;
  int c = (i < N_NODES) ? counts[i] : 0;
  lds[t] = c;
  __syncthreads();
  #pragma unroll
  for (int d = 1; d < 256; d <<= 1) {
    int v = (t >= d) ? lds[t - d] : 0;
    __syncthreads();
    lds[t] += v;
    __syncthreads();
  }
  if (i < N_NODES) offsets[i] = lds[t] - c;
  if (t == 255) blocksums[blockIdx.x] = lds[255];
}

__global__ __launch_bounds__(256) void scan2_kernel(
    const int* __restrict__ blocksums, int* __restrict__ btops,
    int* __restrict__ offsets) {
  __shared__ int lds[256];
  const int t = threadIdx.x;
  int c = (t < SCAN_NB) ? blocksums[t] : 0;
  lds[t] = c;
  __syncthreads();
  #pragma unroll
  for (int d = 1; d < 256; d <<= 1) {
    int v = (t >= d) ? lds[t - d] : 0;
    __syncthreads();
    lds[t] += v;
    __syncthreads();
  }
  if (t < SCAN_NB) btops[t] = lds[t] - c;
  if (t == SCAN_NB - 1) offsets[N_NODES] = lds[t];
}

__global__ __launch_bounds__(256) void scan3_kernel(
    int* __restrict__ offsets, const int* __restrict__ btops,
    int* __restrict__ cursor) {
  const int i = blockIdx.x * 256 + threadIdx.x;
  if (i >= N_NODES) return;
  int o = offsets[i] + btops[blockIdx.x];
  offsets[i] = o;
  cursor[i] = o;
}

// ---- kernel 3: scatter edges into CSR-by-dst -------------------------------
__global__ __launch_bounds__(256) void scatter_kernel(
    const int* __restrict__ src, const int* __restrict__ dst,
    int* __restrict__ cursor, int* __restrict__ csr_src) {
  int e = blockIdx.x * 256 + threadIdx.x;
  int d = dst[e];
  if (d < 0) return;
  int pos = atomicAdd(cursor + d, 1);
  csr_src[pos] = src[e];
}

// ---- kernel 4: x f32 -> bf16 ------------------------------------------------
__global__ __launch_bounds__(256) void cvt_x_kernel(
    const float* __restrict__ x, u16* __restrict__ xb) {
  int i = (blockIdx.x * 256 + threadIdx.x) * 4;
  float4 v = *(const float4*)(x + i);
  u32* o = (u32*)(xb + i);
  o[0] = packbf(v.x, v.y);
  o[1] = packbf(v.z, v.w);
}

// ---- kernel 5: all weights f32 -> bf16 packed ------------------------------
__global__ __launch_bounds__(256) void cvt_w_kernel(
    const float* __restrict__ Wl1, const float* __restrict__ Wr1,
    const float* __restrict__ Wl2, const float* __restrict__ Wr2,
    u16* __restrict__ wb) {
  int i = blockIdx.x * 256 + threadIdx.x;
  if (i < 32768)      wb[i] = f2bf(Wl1[i]);
  else if (i < 65536) wb[i] = f2bf(Wr1[i - 32768]);
  else if (i < 75776) wb[i] = f2bf(Wl2[i - 65536]);
  else if (i < 86016) wb[i] = f2bf(Wr2[i - 75776]);
}

// ---- kernel 6: layer-1 mean aggregation, 4-way unrolled MLP ----------------
__global__ __launch_bounds__(256) void gather1_kernel(
    const u16* __restrict__ xb, const int* __restrict__ offsets,
    const int* __restrict__ csr_src, u16* __restrict__ agg1) {
  const int node = blockIdx.x * 4 + (threadIdx.x >> 6);
  const int lane = threadIdx.x & 63;
  int b = offsets[node], e = offsets[node + 1];
  float a0 = 0.f, a1 = 0.f, b0 = 0.f, b1 = 0.f;
  float c0 = 0.f, c1 = 0.f, d0 = 0.f, d1 = 0.f;
  int i = b;
  for (; i + 4 <= e; i += 4) {
    int s0 = csr_src[i], s1 = csr_src[i + 1], s2 = csr_src[i + 2], s3 = csr_src[i + 3];
    u32 w0 = ((const u32*)(xb + (size_t)s0 * D_FEAT))[lane];
    u32 w1 = ((const u32*)(xb + (size_t)s1 * D_FEAT))[lane];
    u32 w2 = ((const u32*)(xb + (size_t)s2 * D_FEAT))[lane];
    u32 w3 = ((const u32*)(xb + (size_t)s3 * D_FEAT))[lane];
    a0 += bf_lo(w0); a1 += bf_hi(w0);
    b0 += bf_lo(w1); b1 += bf_hi(w1);
    c0 += bf_lo(w2); c1 += bf_hi(w2);
    d0 += bf_lo(w3); d1 += bf_hi(w3);
  }
  for (; i < e; i++) {
    int s = csr_src[i];
    u32 w = ((const u32*)(xb + (size_t)s * D_FEAT))[lane];
    a0 += bf_lo(w); a1 += bf_hi(w);
  }
  float s0 = (a0 + b0) + (c0 + d0);
  float s1 = (a1 + b1) + (c1 + d1);
  float inv = 1.0f / (float)max(e - b, 1);
  ((u32*)(agg1 + (size_t)node * D_FEAT))[lane] = packbf(s0 * inv, s1 * inv);
}

// ---- kernel 7: layer-1 GEMM via MFMA (R4/R5-verified) ----------------------
__global__ __launch_bounds__(256) void gemm1_mfma_kernel(
    const u16* __restrict__ agg1, const u16* __restrict__ xb,
    const u16* __restrict__ Wl1b, const u16* __restrict__ Wr1b,
    const float* __restrict__ bl1, u16* __restrict__ h) {
  const int lane = threadIdx.x & 63;
  const int wave = threadIdx.x >> 6;
  const int m0 = blockIdx.x * 16;
  const int ra = m0 + (lane & 15);
  const int ko = (lane >> 4) * 8;
  const int nb = wave * 64 + (lane & 15);

  floatx4 acc[4];
  #pragma unroll
  for (int t = 0; t < 4; t++) acc[t] = floatx4{0.f, 0.f, 0.f, 0.f};

  #pragma unroll
  for (int ph = 0; ph < 2; ph++) {
    const u16* A = (ph == 0 ? agg1 : xb) + (size_t)ra * D_FEAT + ko;
    const u16* W = (ph == 0 ? Wl1b : Wr1b);
    #pragma unroll
    for (int kk = 0; kk < D_FEAT; kk += 32) {
      short8 a = *(const short8*)(A + kk);
      #pragma unroll
      for (int t = 0; t < 4; t++) {
        short8 b = *(const short8*)(W + (size_t)(nb + t * 16) * D_FEAT + ko + kk);
        acc[t] = __builtin_amdgcn_mfma_f32_16x16x32_bf16(a, b, acc[t], 0, 0, 0);
      }
    }
  }

  #pragma unroll
  for (int t = 0; t < 4; t++) {
    int col = wave * 64 + t * 16 + (lane & 15);
    float bias = bl1[col];
    #pragma unroll
    for (int r = 0; r < 4; r++) {
      int row = m0 + (lane >> 4) * 4 + r;
      float v = acc[t][r] + bias;
      v = v > 0.f ? v : 0.f;
      h[(size_t)row * HIDDEN + col] = f2bf(v);
    }
  }
}

// ---- kernel 8: layer-2 dual projection via MFMA (R6-verified) --------------
__global__ __launch_bounds__(256) void gemm2ab_kernel(
    const u16* __restrict__ h, const u16* __restrict__ Wl2b,
    const u16* __restrict__ Wr2b, const float* __restrict__ bl2,
    u16* __restrict__ p2b, float* __restrict__ r2f) {
  const int lane = threadIdx.x & 63;
  const int wave = threadIdx.x >> 6;
  const int tile = blockIdx.x * 4 + wave;
  if (tile >= N_NODES / 16) return;
  const int m0 = tile * 16;
  const int ra = m0 + (lane & 15);
  const int ko = (lane >> 4) * 8;
  const int n15 = lane & 15;
  const int nrow0 = n15;
  const int nrow1 = 16 + n15;
  const int nrow2 = min(32 + n15, CLASSES - 1);  // clamp; lands in pad cols

  floatx4 accp[3], accr[3];
  #pragma unroll
  for (int t = 0; t < 3; t++) {
    accp[t] = floatx4{0.f, 0.f, 0.f, 0.f};
    accr[t] = floatx4{0.f, 0.f, 0.f, 0.f};
  }

  const u16* A  = h + (size_t)ra * HIDDEN + ko;
  const u16* L0 = Wl2b + (size_t)nrow0 * HIDDEN + ko;
  const u16* L1 = Wl2b + (size_t)nrow1 * HIDDEN + ko;
  const u16* L2 = Wl2b + (size_t)nrow2 * HIDDEN + ko;
  const u16* R0 = Wr2b + (size_t)nrow0 * HIDDEN + ko;
  const u16* R1 = Wr2b + (size_t)nrow1 * HIDDEN + ko;
  const u16* R2 = Wr2b + (size_t)nrow2 * HIDDEN + ko;

  #pragma unroll
  for (int kk = 0; kk < HIDDEN; kk += 32) {
    short8 a = *(const short8*)(A + kk);
    accp[0] = __builtin_amdgcn_mfma_f32_16x16x32_bf16(a, *(const short8*)(L0 + kk), accp[0], 0, 0, 0);
    accp[1] = __builtin_amdgcn_mfma_f32_16x16x32_bf16(a, *(const short8*)(L1 + kk), accp[1], 0, 0, 0);
    accp[2] = __builtin_amdgcn_mfma_f32_16x16x32_bf16(a, *(const short8*)(L2 + kk), accp[2], 0, 0, 0);
    accr[0] = __builtin_amdgcn_mfma_f32_16x16x32_bf16(a, *(const short8*)(R0 + kk), accr[0], 0, 0, 0);
    accr[1] = __builtin_amdgcn_mfma_f32_16x16x32_bf16(a, *(const short8*)(R1 + kk), accr[1], 0, 0, 0);
    accr[2] = __builtin_amdgcn_mfma_f32_16x16x32_bf16(a, *(const short8*)(R2 + kk), accr[2], 0, 0, 0);
  }

  #pragma unroll
  for (int t = 0; t < 3; t++) {
    int col = t * 16 + n15;
    float bias = bl2[min(col, CLASSES - 1)];
    #pragma unroll
    for (int r = 0; r < 4; r++) {
      int row = m0 + (lane >> 4) * 4 + r;
      p2b[(size_t)row * P2S + col] = f2bf(accp[t][r]);
      r2f[(size_t)row * R2S + col] = accr[t][r] + bias;
    }
  }
}

// ---- kernel 9: fused mean-gather + log_softmax, 4-way unrolled MLP ---------
__global__ __launch_bounds__(256) void final_kernel(
    const u16* __restrict__ p2b, const float* __restrict__ r2f,
    const int* __restrict__ offsets, const int* __restrict__ csr_src,
    float* __restrict__ out) {
  const int node = blockIdx.x * 4 + (threadIdx.x >> 6);
  const int lane = threadIdx.x & 63;
  int b = offsets[node], e = offsets[node + 1];
  float s0 = 0.f, s1 = 0.f, s2 = 0.f, s3 = 0.f;
  int i = b;
  for (; i + 4 <= e; i += 4) {
    int c0 = csr_src[i], c1 = csr_src[i + 1], c2 = csr_src[i + 2], c3 = csr_src[i + 3];
    s0 += bf1(p2b[(size_t)c0 * P2S + lane]);
    s1 += bf1(p2b[(size_t)c1 * P2S + lane]);
    s2 += bf1(p2b[(size_t)c2 * P2S + lane]);
    s3 += bf1(p2b[(size_t)c3 * P2S + lane]);
  }
  for (; i < e; i++) {
    int sc = csr_src[i];
    s0 += bf1(p2b[(size_t)sc * P2S + lane]);
  }
  float s = (s0 + s1) + (s2 + s3);
  float inv = 1.0f / (float)max(e - b, 1);
  const bool act = (lane < CLASSES);
  float v = act ? (s * inv + r2f[(size_t)node * R2S + lane]) : -INFINITY;
  float mx = v;
  #pragma unroll
  for (int d = 1; d < 64; d <<= 1) mx = fmaxf(mx, __shfl_xor(mx, d, 64));
  float ex = act ? expf(v - mx) : 0.f;
  float sum = ex;
  #pragma unroll
  for (int d = 1; d < 64; d <<= 1) sum += __shfl_xor(sum, d, 64);
  float l = mx + logf(sum);
  if (act) out[(size_t)node * CLASSES + lane] = v - l;
}

extern "C" void kernel_launch(void* const* d_in, const int* in_sizes, int n_in,
                              void* d_out, int out_size, void* d_ws, size_t ws_size,
                              hipStream_t stream) {
  const float* x   = (const float*)d_in[0];
  const void*  ei  = d_in[1];
  const float* Wl1 = (const float*)d_in[2];
  const float* bl1 = (const float*)d_in[3];
  const float* Wr1 = (const float*)d_in[4];
  const float* Wl2 = (const float*)d_in[5];
  const float* bl2 = (const float*)d_in[6];
  const float* Wr2 = (const float*)d_in[7];

  char* ws = (char*)d_ws;
  size_t off = 0;
  int* flag      = (int*)(ws + off); off += 256;
  int* src       = (int*)(ws + off); off += (size_t)N_EDGES * 4;             // 3.2MB
  int* dst       = (int*)(ws + off); off += (size_t)N_EDGES * 4;             // 3.2MB
  int* csr       = (int*)(ws + off); off += (size_t)N_EDGES * 4;             // 3.2MB
  int* counts    = (int*)(ws + off); off += 200192;
  int* offsets   = (int*)(ws + off); off += 200192;
  int* cursor    = (int*)(ws + off); off += 200192;
  int* blocksums = (int*)(ws + off); off += 1024;
  int* btops     = (int*)(ws + off); off += 1024;
  u16* wb        = (u16*)(ws + off); off += 172288;                          // 86016 bf16 padded
  u16* xb        = (u16*)(ws + off); off += (size_t)N_NODES * D_FEAT * 2;    // 12.8MB
  u16* agg1      = (u16*)(ws + off); off += (size_t)N_NODES * D_FEAT * 2;    // 12.8MB
  u16* hbuf      = (u16*)(ws + off); off += (size_t)N_NODES * HIDDEN * 2;    // 25.6MB
  u16* p2b       = (u16*)(ws + off); off += (size_t)N_NODES * P2S * 2;       // 6.4MB
  float* r2f     = (float*)(ws + off); off += (size_t)N_NODES * R2S * 4;     // 9.6MB

  u16* Wl1b = wb;
  u16* Wr1b = wb + 32768;
  u16* Wl2b = wb + 65536;
  u16* Wr2b = wb + 75776;

  hipMemsetAsync(counts, 0, (size_t)N_NODES * 4, stream);
  detect_kernel<<<1, 256, 0, stream>>>((const long long*)ei, flag);
  convert_hist_kernel<<<N_EDGES / 256, 256, 0, stream>>>(ei, flag, src, dst, counts);
  scan1_kernel<<<SCAN_NB, 256, 0, stream>>>(counts, offsets, blocksums);
  scan2_kernel<<<1, 256, 0, stream>>>(blocksums, btops, offsets);
  scan3_kernel<<<SCAN_NB, 256, 0, stream>>>(offsets, btops, cursor);
  scatter_kernel<<<N_EDGES / 256, 256, 0, stream>>>(src, dst, cursor, csr);
  cvt_x_kernel<<<(N_NODES * D_FEAT) / (256 * 4), 256, 0, stream>>>(x, xb);
  cvt_w_kernel<<<(86016 + 255) / 256, 256, 0, stream>>>(Wl1, Wr1, Wl2, Wr2, wb);
  gather1_kernel<<<N_NODES / 4, 256, 0, stream>>>(xb, offsets, csr, agg1);
  gemm1_mfma_kernel<<<N_NODES / 16, 256, 0, stream>>>(agg1, xb, Wl1b, Wr1b, bl1, hbuf);
  gemm2ab_kernel<<<(N_NODES / 16 + 3) / 4, 256, 0, stream>>>(hbuf, Wl2b, Wr2b, bl2, p2b, r2f);
  final_kernel<<<N_NODES / 4, 256, 0, stream>>>(p2b, r2f, offsets, csr, (float*)d_out);
}